// Round 1
// baseline (237.650 us; speedup 1.0000x reference)
//
#include <hip/hip_runtime.h>
#include <hip/hip_bf16.h>

// N3 aggregation: C=64, E=32, H=W=128, K=7, PS=7 (PR=3), WS=13 (WR=6), O=169
#define HW 16384

using u16 = unsigned short;
using u32 = unsigned int;

__device__ __forceinline__ float bf2f(u16 u) {
    u32 x = ((u32)u) << 16;
    return __uint_as_float(x);
}
__device__ __forceinline__ u16 f2bf(float f) {  // round-to-nearest-even
    u32 b = __float_as_uint(f);
    u32 r = (b + 0x7FFFu + ((b >> 16) & 1u)) >> 16;
    return (u16)r;
}

// ---------------------------------------------------------------------------
// K0: transposes + temperature. grid 64 x 256. one thread per pixel.
//   xT  [y][64] bf16, xeT [y][32] f32, yeT [y][32] f32, tinv[y] = exp(-boxsum(lt)/49)
// ---------------------------------------------------------------------------
__global__ __launch_bounds__(256) void k_prep(
        const float* __restrict__ x, const float* __restrict__ xe,
        const float* __restrict__ ye, const float* __restrict__ lt,
        u16* __restrict__ xT, float* __restrict__ xeT,
        float* __restrict__ yeT, float* __restrict__ tinv) {
    int y = blockIdx.x * 256 + threadIdx.x;
    int py = y >> 7, px = y & 127;

    u16* xrow = xT + y * 64;
#pragma unroll
    for (int c0 = 0; c0 < 64; c0 += 8) {
        u32 w[4];
#pragma unroll
        for (int q = 0; q < 4; q++) {
            u16 a = f2bf(x[(c0 + 2 * q) * HW + y]);
            u16 b = f2bf(x[(c0 + 2 * q + 1) * HW + y]);
            w[q] = (u32)a | ((u32)b << 16);
        }
        *reinterpret_cast<uint4*>(xrow + c0) = make_uint4(w[0], w[1], w[2], w[3]);
    }
#pragma unroll
    for (int e0 = 0; e0 < 32; e0 += 4) {
        float4 v = make_float4(xe[(e0 + 0) * HW + y], xe[(e0 + 1) * HW + y],
                               xe[(e0 + 2) * HW + y], xe[(e0 + 3) * HW + y]);
        *reinterpret_cast<float4*>(xeT + y * 32 + e0) = v;
        float4 u = make_float4(ye[(e0 + 0) * HW + y], ye[(e0 + 1) * HW + y],
                               ye[(e0 + 2) * HW + y], ye[(e0 + 3) * HW + y]);
        *reinterpret_cast<float4*>(yeT + y * 32 + e0) = u;
    }
    float s = 0.f;
    for (int dy = -3; dy <= 3; dy++)
        for (int dx = -3; dx <= 3; dx++) {
            int yy = py + dy, xx = px + dx;
            if ((unsigned)yy < 128u && (unsigned)xx < 128u) s += lt[yy * 128 + xx];
        }
    tinv[y] = __expf(-s * (1.0f / 49.0f));
}

// ---------------------------------------------------------------------------
// K1: fused diff2 + 7x7 boxsum -> logits[o][y] f32.
// grid (13 di-rows, 64 tiles of 16x16), 512 threads.
// halo pixels z = tile +-3; xs shift = (di-6, dj-6) staged with 6-halo in LDS.
// ---------------------------------------------------------------------------
__global__ __launch_bounds__(512) void k_logits(
        const float* __restrict__ xeT, const float* __restrict__ yeT,
        const float* __restrict__ tinv, float* __restrict__ logits) {
    __shared__ float s_xe[22 * 34 * 36];  // [zr*34+zc(+dj)][e 32 pad36]
    __shared__ float s_d2[22 * 22];
    __shared__ float s_hs[22 * 16];

    int di = blockIdx.x;
    int tile = blockIdx.y;
    int h0 = (tile >> 3) * 16, w0 = (tile & 7) * 16;
    int gr0 = h0 + di - 9, gc0 = w0 - 9;
    int tid = threadIdx.x;

    for (int idx = tid; idx < 22 * 34 * 8; idx += 512) {
        int cell = idx >> 3, ch = idx & 7;
        int r = cell / 34, c = cell - r * 34;
        int gy = gr0 + r, gx = gc0 + c;
        float4 v = make_float4(0.f, 0.f, 0.f, 0.f);
        if ((unsigned)gy < 128u && (unsigned)gx < 128u)
            v = *reinterpret_cast<const float4*>(xeT + (gy * 128 + gx) * 32 + ch * 4);
        *reinterpret_cast<float4*>(s_xe + cell * 36 + ch * 4) = v;
    }

    int hp = tid;
    int zr = hp / 22, zc = hp - zr * 22;
    int gy = h0 - 3 + zr, gx = w0 - 3 + zc;
    bool zin = (hp < 484) && ((unsigned)gy < 128u) && ((unsigned)gx < 128u);
    float4 yr[8];
#pragma unroll
    for (int ch = 0; ch < 8; ch++) yr[ch] = make_float4(0.f, 0.f, 0.f, 0.f);
    if (zin) {
#pragma unroll
        for (int ch = 0; ch < 8; ch++)
            yr[ch] = *reinterpret_cast<const float4*>(yeT + (gy * 128 + gx) * 32 + ch * 4);
    }
    __syncthreads();

    for (int dj = 0; dj < 13; dj++) {
        if (hp < 484) {
            float d2 = 0.f;
            if (zin) {
                const float* base = s_xe + (zr * 34 + zc + dj) * 36;
#pragma unroll
                for (int ch = 0; ch < 8; ch++) {
                    float4 q = *reinterpret_cast<const float4*>(base + ch * 4);
                    float a = yr[ch].x - q.x, b = yr[ch].y - q.y;
                    float c2 = yr[ch].z - q.z, d = yr[ch].w - q.w;
                    d2 += a * a; d2 += b * b; d2 += c2 * c2; d2 += d * d;
                }
            }
            s_d2[hp] = d2;
        }
        __syncthreads();
        if (tid < 352) {  // horizontal: 22 halo rows x 16 out cols
            int r = tid >> 4, c = tid & 15;
            float s = 0.f;
#pragma unroll
            for (int d = 0; d < 7; d++) s += s_d2[r * 22 + c + d];
            s_hs[r * 16 + c] = s;
        }
        __syncthreads();
        if (tid < 256) {  // vertical: 16x16 outputs
            int i = tid >> 4, jj = tid & 15;
            float s = 0.f;
#pragma unroll
            for (int d = 0; d < 7; d++) s += s_hs[(i + d) * 16 + jj];
            int y = (h0 + i) * 128 + (w0 + jj);
            int o = di * 13 + dj;
            logits[o * HW + y] = -tinv[y] * s;
        }
        __syncthreads();
    }
}

// ---------------------------------------------------------------------------
// K2: K=7 rounds of exclusion softmax over O=169. grid 256 x 256.
// 64 pixels/block, 4 lanes per pixel (o strided by 4), logits in registers.
// writes Wkt[o][y][k (pad8)] bf16.
// ---------------------------------------------------------------------------
__global__ __launch_bounds__(256) void k_softmax(
        const float* __restrict__ logits, u16* __restrict__ Wkt) {
    __shared__ float s_lg[169 * 66];
    int tid = threadIdx.x;
    int y0 = blockIdx.x * 64;
    for (int idx = tid; idx < 169 * 64; idx += 256) {
        int o = idx >> 6, p = idx & 63;
        s_lg[o * 66 + p] = logits[o * HW + y0 + p];
    }
    __syncthreads();
    int pix = tid >> 2, t = tid & 3;
    int y = y0 + pix;
    float l[43];
#pragma unroll
    for (int j = 0; j < 43; j++) {
        int o = t + 4 * j;
        l[j] = (o < 169) ? s_lg[o * 66 + pix] : -3e38f;
    }
#pragma unroll 1
    for (int k = 0; k < 7; k++) {
        float m = -3e38f;
#pragma unroll
        for (int j = 0; j < 43; j++) m = fmaxf(m, l[j]);
        m = fmaxf(m, __shfl_xor(m, 1));
        m = fmaxf(m, __shfl_xor(m, 2));
        float s = 0.f;
#pragma unroll
        for (int j = 0; j < 43; j++) s += __expf(l[j] - m);
        s += __shfl_xor(s, 1);
        s += __shfl_xor(s, 2);
        float rs = 1.0f / s;
#pragma unroll
        for (int j = 0; j < 43; j++) {
            int o = t + 4 * j;
            if (o < 169) {
                float w = __expf(l[j] - m) * rs;
                Wkt[(o * HW + y) * 8 + k] = f2bf(w);
                l[j] += __logf(fmaxf(1.0f - w, 1e-6f));
            }
        }
    }
}

// ---------------------------------------------------------------------------
// K2b: 7x7 boxsum of Wkt -> WsT[o][y][k8] bf16. grid (169, 16 tiles of 32x32).
// separable sliding-window, vectorized over packed k.
// ---------------------------------------------------------------------------
__global__ __launch_bounds__(256) void k_wsum(
        const u16* __restrict__ Wkt, u16* __restrict__ WsT) {
    __shared__ u16 s_w[38 * 38 * 8];
    __shared__ float s_v[32 * 38 * 8];
    int o = blockIdx.x;
    int tile = blockIdx.y;
    int h0 = (tile >> 2) * 32, w0 = (tile & 3) * 32;
    int tid = threadIdx.x;

    for (int idx = tid; idx < 38 * 38; idx += 256) {
        int r = idx / 38, c = idx - r * 38;
        int gy = h0 - 3 + r, gx = w0 - 3 + c;
        uint4 v = make_uint4(0u, 0u, 0u, 0u);
        if ((unsigned)gy < 128u && (unsigned)gx < 128u)
            v = *reinterpret_cast<const uint4*>(Wkt + (o * HW + gy * 128 + gx) * 8);
        *reinterpret_cast<uint4*>(s_w + idx * 8) = v;
    }
    __syncthreads();

    if (tid < 152) {  // vertical: 38 cols x 4 groups of 8 out-rows
        int c = tid >> 2, g = tid & 3;
        int r0 = g * 8;
        float acc[7];
#pragma unroll
        for (int k = 0; k < 7; k++) acc[k] = 0.f;
#pragma unroll
        for (int d = 0; d < 7; d++) {
            uint4 q = *reinterpret_cast<const uint4*>(s_w + ((r0 + d) * 38 + c) * 8);
            acc[0] += bf2f((u16)(q.x & 0xffffu)); acc[1] += bf2f((u16)(q.x >> 16));
            acc[2] += bf2f((u16)(q.y & 0xffffu)); acc[3] += bf2f((u16)(q.y >> 16));
            acc[4] += bf2f((u16)(q.z & 0xffffu)); acc[5] += bf2f((u16)(q.z >> 16));
            acc[6] += bf2f((u16)(q.w & 0xffffu));
        }
#pragma unroll
        for (int k = 0; k < 7; k++) s_v[(r0 * 38 + c) * 8 + k] = acc[k];
        for (int i = 1; i < 8; i++) {
            uint4 qn = *reinterpret_cast<const uint4*>(s_w + ((r0 + i + 6) * 38 + c) * 8);
            uint4 qo = *reinterpret_cast<const uint4*>(s_w + ((r0 + i - 1) * 38 + c) * 8);
            acc[0] += bf2f((u16)(qn.x & 0xffffu)) - bf2f((u16)(qo.x & 0xffffu));
            acc[1] += bf2f((u16)(qn.x >> 16)) - bf2f((u16)(qo.x >> 16));
            acc[2] += bf2f((u16)(qn.y & 0xffffu)) - bf2f((u16)(qo.y & 0xffffu));
            acc[3] += bf2f((u16)(qn.y >> 16)) - bf2f((u16)(qo.y >> 16));
            acc[4] += bf2f((u16)(qn.z & 0xffffu)) - bf2f((u16)(qo.z & 0xffffu));
            acc[5] += bf2f((u16)(qn.z >> 16)) - bf2f((u16)(qo.z >> 16));
            acc[6] += bf2f((u16)(qn.w & 0xffffu)) - bf2f((u16)(qo.w & 0xffffu));
#pragma unroll
            for (int k = 0; k < 7; k++) s_v[((r0 + i) * 38 + c) * 8 + k] = acc[k];
        }
    }
    __syncthreads();

    if (tid < 128) {  // horizontal: 32 rows x 4 groups of 8 out-cols
        int r = tid >> 2, g = tid & 3;
        int c0 = g * 8;
        float acc[7];
#pragma unroll
        for (int k = 0; k < 7; k++) acc[k] = 0.f;
        for (int d = 0; d < 7; d++) {
#pragma unroll
            for (int k = 0; k < 7; k++) acc[k] += s_v[(r * 38 + c0 + d) * 8 + k];
        }
        for (int i = 0; i < 8; i++) {
            if (i > 0) {
#pragma unroll
                for (int k = 0; k < 7; k++)
                    acc[k] += s_v[(r * 38 + c0 + i + 6) * 8 + k] - s_v[(r * 38 + c0 + i - 1) * 8 + k];
            }
            u32 p0 = (u32)f2bf(acc[0]) | ((u32)f2bf(acc[1]) << 16);
            u32 p1 = (u32)f2bf(acc[2]) | ((u32)f2bf(acc[3]) << 16);
            u32 p2 = (u32)f2bf(acc[4]) | ((u32)f2bf(acc[5]) << 16);
            u32 p3 = (u32)f2bf(acc[6]);
            int y = (h0 + r) * 128 + (w0 + c0 + i);
            *reinterpret_cast<uint4*>(WsT + (o * HW + y) * 8) = make_uint4(p0, p1, p2, p3);
        }
    }
}

// ---------------------------------------------------------------------------
// K3: aggregation. out[k,c,y] = sum_o WsT[o,y,k] * x[c, y+off(o)].
// grid 256 tiles of 4x16 pixels, 512 threads = 64 pixels x 8 c-chunks.
// acc[7][8] in registers: x value reused across all 7 k.
// ---------------------------------------------------------------------------
__global__ __launch_bounds__(512) void k_agg(
        const u16* __restrict__ xT, const u16* __restrict__ WsT,
        float* __restrict__ out) {
    __shared__ u16 s_x[448 * 68];     // [16r x 28c][64ch pad 68]
    __shared__ u16 s_ws[7 * 64 * 12]; // [j][pix][8k pad 12]
    int tb = blockIdx.x;
    int h0 = (tb >> 3) * 4, w0 = (tb & 7) * 16;
    int tid = threadIdx.x;

    for (int idx = tid; idx < 448 * 16; idx += 512) {
        int cell = idx >> 4, ch = idx & 15;
        int r = cell / 28, c = cell - r * 28;
        int gy = h0 - 6 + r, gx = w0 - 6 + c;
        uint2 v = make_uint2(0u, 0u);
        if ((unsigned)gy < 128u && (unsigned)gx < 128u)
            v = *reinterpret_cast<const uint2*>(xT + (gy * 128 + gx) * 64 + ch * 4);
        *reinterpret_cast<uint2*>(s_x + cell * 68 + ch * 4) = v;
    }

    int cc = tid >> 6, pix = tid & 63;
    int pr = pix >> 4, pc = pix & 15;
    int y = (h0 + pr) * 128 + (w0 + pc);
    float acc[7][8];
#pragma unroll
    for (int k = 0; k < 7; k++)
#pragma unroll
        for (int q = 0; q < 8; q++) acc[k][q] = 0.f;

    for (int oc = 0; oc < 25; oc++) {
        int o0 = oc * 7;
        int nj = (169 - o0 < 7) ? (169 - o0) : 7;
        __syncthreads();
        if (tid < nj * 64) {
            int j = tid >> 6, p = tid & 63;
            int yy = (h0 + (p >> 4)) * 128 + (w0 + (p & 15));
            uint4 q = *reinterpret_cast<const uint4*>(WsT + ((o0 + j) * HW + yy) * 8);
            *reinterpret_cast<uint2*>(s_ws + (j * 64 + p) * 12) = make_uint2(q.x, q.y);
            *reinterpret_cast<uint2*>(s_ws + (j * 64 + p) * 12 + 4) = make_uint2(q.z, q.w);
        }
        __syncthreads();
#pragma unroll 1
        for (int j = 0; j < nj; j++) {
            int o = o0 + j;
            int di = o / 13, dj = o - di * 13;
            uint2 wa = *reinterpret_cast<const uint2*>(s_ws + (j * 64 + pix) * 12);
            uint2 wb = *reinterpret_cast<const uint2*>(s_ws + (j * 64 + pix) * 12 + 4);
            float wv[7];
            wv[0] = bf2f((u16)(wa.x & 0xffffu)); wv[1] = bf2f((u16)(wa.x >> 16));
            wv[2] = bf2f((u16)(wa.y & 0xffffu)); wv[3] = bf2f((u16)(wa.y >> 16));
            wv[4] = bf2f((u16)(wb.x & 0xffffu)); wv[5] = bf2f((u16)(wb.x >> 16));
            wv[6] = bf2f((u16)(wb.y & 0xffffu));
            int cell = (pr + di) * 28 + (pc + dj);
            const u16* xp = s_x + cell * 68 + cc * 8;
            uint2 xa = *reinterpret_cast<const uint2*>(xp);
            uint2 xb = *reinterpret_cast<const uint2*>(xp + 4);
            float xv[8];
            xv[0] = bf2f((u16)(xa.x & 0xffffu)); xv[1] = bf2f((u16)(xa.x >> 16));
            xv[2] = bf2f((u16)(xa.y & 0xffffu)); xv[3] = bf2f((u16)(xa.y >> 16));
            xv[4] = bf2f((u16)(xb.x & 0xffffu)); xv[5] = bf2f((u16)(xb.x >> 16));
            xv[6] = bf2f((u16)(xb.y & 0xffffu)); xv[7] = bf2f((u16)(xb.y >> 16));
#pragma unroll
            for (int k = 0; k < 7; k++)
#pragma unroll
                for (int q = 0; q < 8; q++)
                    acc[k][q] = fmaf(wv[k], xv[q], acc[k][q]);
        }
    }
#pragma unroll
    for (int k = 0; k < 7; k++)
#pragma unroll
        for (int q = 0; q < 8; q++)
            out[(k * 64 + cc * 8 + q) * HW + y] = acc[k][q];
}

// ---------------------------------------------------------------------------
extern "C" void kernel_launch(void* const* d_in, const int* in_sizes, int n_in,
                              void* d_out, int out_size, void* d_ws, size_t ws_size,
                              hipStream_t stream) {
    (void)in_sizes; (void)n_in; (void)out_size; (void)ws_size;
    const float* x  = (const float*)d_in[0];
    const float* xe = (const float*)d_in[1];
    const float* ye = (const float*)d_in[2];
    const float* lt = (const float*)d_in[3];
    float* out = (float*)d_out;
    char* ws = (char*)d_ws;

    u16*   xT     = (u16*)(ws + 0);            //  2,097,152 B
    float* xeT    = (float*)(ws + 2097152u);   //  2,097,152
    float* yeT    = (float*)(ws + 4194304u);   //  2,097,152
    float* tinv   = (float*)(ws + 6291456u);   //     65,536
    float* logits = (float*)(ws + 6356992u);   // 11,075,584
    u16*   Wkt    = (u16*)(ws + 17432576u);    // 44,302,336
    u16*   WsT    = (u16*)(ws + 61734912u);    // 44,302,336 -> ends 106,037,248

    k_prep<<<64, 256, 0, stream>>>(x, xe, ye, lt, xT, xeT, yeT, tinv);
    k_logits<<<dim3(13, 64), 512, 0, stream>>>(xeT, yeT, tinv, logits);
    k_softmax<<<256, 256, 0, stream>>>(logits, Wkt);
    k_wsum<<<dim3(169, 16), 256, 0, stream>>>(Wkt, WsT);
    k_agg<<<256, 512, 0, stream>>>(xT, WsT, out);
}

// Round 2
// 190.921 us; speedup vs baseline: 1.2448x; 1.2448x over previous
//
#include <hip/hip_runtime.h>
#include <hip/hip_bf16.h>

// N3 aggregation: C=64, E=32, H=W=128, K=7, PS=7 (PR=3), WS=13 (WR=6), O=169
#define HW 16384

using u16 = unsigned short;
using u32 = unsigned int;

__device__ __forceinline__ float bf2f(u16 u) {
    u32 x = ((u32)u) << 16;
    return __uint_as_float(x);
}
__device__ __forceinline__ u16 f2bf(float f) {  // round-to-nearest-even
    u32 b = __float_as_uint(f);
    u32 r = (b + 0x7FFFu + ((b >> 16) & 1u)) >> 16;
    return (u16)r;
}

// ---------------------------------------------------------------------------
// K0: transposes + temperature. grid 64 x 256. one thread per pixel.
//   xT  [y][64] bf16, xeT [y][32] f32, yeT [y][32] f32, tinv[y] = exp(-boxsum(lt)/49)
// ---------------------------------------------------------------------------
__global__ __launch_bounds__(256) void k_prep(
        const float* __restrict__ x, const float* __restrict__ xe,
        const float* __restrict__ ye, const float* __restrict__ lt,
        u16* __restrict__ xT, float* __restrict__ xeT,
        float* __restrict__ yeT, float* __restrict__ tinv) {
    int y = blockIdx.x * 256 + threadIdx.x;
    int py = y >> 7, px = y & 127;

    u16* xrow = xT + y * 64;
#pragma unroll
    for (int c0 = 0; c0 < 64; c0 += 8) {
        u32 w[4];
#pragma unroll
        for (int q = 0; q < 4; q++) {
            u16 a = f2bf(x[(c0 + 2 * q) * HW + y]);
            u16 b = f2bf(x[(c0 + 2 * q + 1) * HW + y]);
            w[q] = (u32)a | ((u32)b << 16);
        }
        *reinterpret_cast<uint4*>(xrow + c0) = make_uint4(w[0], w[1], w[2], w[3]);
    }
#pragma unroll
    for (int e0 = 0; e0 < 32; e0 += 4) {
        float4 v = make_float4(xe[(e0 + 0) * HW + y], xe[(e0 + 1) * HW + y],
                               xe[(e0 + 2) * HW + y], xe[(e0 + 3) * HW + y]);
        *reinterpret_cast<float4*>(xeT + y * 32 + e0) = v;
        float4 u = make_float4(ye[(e0 + 0) * HW + y], ye[(e0 + 1) * HW + y],
                               ye[(e0 + 2) * HW + y], ye[(e0 + 3) * HW + y]);
        *reinterpret_cast<float4*>(yeT + y * 32 + e0) = u;
    }
    float s = 0.f;
    for (int dy = -3; dy <= 3; dy++)
        for (int dx = -3; dx <= 3; dx++) {
            int yy = py + dy, xx = px + dx;
            if ((unsigned)yy < 128u && (unsigned)xx < 128u) s += lt[yy * 128 + xx];
        }
    tinv[y] = __expf(-s * (1.0f / 49.0f));
}

// ---------------------------------------------------------------------------
// K1: fused diff2 + 7x7 boxsum -> logits[o][y] f32.
// grid (13 di-rows, 64 tiles of 16x16), 512 threads.
// halo pixels z = tile +-3; xs shift = (di-6, dj-6) staged with 6-halo in LDS.
// ---------------------------------------------------------------------------
__global__ __launch_bounds__(512) void k_logits(
        const float* __restrict__ xeT, const float* __restrict__ yeT,
        const float* __restrict__ tinv, float* __restrict__ logits) {
    __shared__ float s_xe[22 * 34 * 36];  // [zr*34+zc(+dj)][e 32 pad36]
    __shared__ float s_d2[22 * 22];
    __shared__ float s_hs[22 * 16];

    int di = blockIdx.x;
    int tile = blockIdx.y;
    int h0 = (tile >> 3) * 16, w0 = (tile & 7) * 16;
    int gr0 = h0 + di - 9, gc0 = w0 - 9;
    int tid = threadIdx.x;

    for (int idx = tid; idx < 22 * 34 * 8; idx += 512) {
        int cell = idx >> 3, ch = idx & 7;
        int r = cell / 34, c = cell - r * 34;
        int gy = gr0 + r, gx = gc0 + c;
        float4 v = make_float4(0.f, 0.f, 0.f, 0.f);
        if ((unsigned)gy < 128u && (unsigned)gx < 128u)
            v = *reinterpret_cast<const float4*>(xeT + (gy * 128 + gx) * 32 + ch * 4);
        *reinterpret_cast<float4*>(s_xe + cell * 36 + ch * 4) = v;
    }

    int hp = tid;
    int zr = hp / 22, zc = hp - zr * 22;
    int gy = h0 - 3 + zr, gx = w0 - 3 + zc;
    bool zin = (hp < 484) && ((unsigned)gy < 128u) && ((unsigned)gx < 128u);
    float4 yr[8];
#pragma unroll
    for (int ch = 0; ch < 8; ch++) yr[ch] = make_float4(0.f, 0.f, 0.f, 0.f);
    if (zin) {
#pragma unroll
        for (int ch = 0; ch < 8; ch++)
            yr[ch] = *reinterpret_cast<const float4*>(yeT + (gy * 128 + gx) * 32 + ch * 4);
    }
    __syncthreads();

    for (int dj = 0; dj < 13; dj++) {
        if (hp < 484) {
            float d2 = 0.f;
            if (zin) {
                const float* base = s_xe + (zr * 34 + zc + dj) * 36;
#pragma unroll
                for (int ch = 0; ch < 8; ch++) {
                    float4 q = *reinterpret_cast<const float4*>(base + ch * 4);
                    float a = yr[ch].x - q.x, b = yr[ch].y - q.y;
                    float c2 = yr[ch].z - q.z, d = yr[ch].w - q.w;
                    d2 += a * a; d2 += b * b; d2 += c2 * c2; d2 += d * d;
                }
            }
            s_d2[hp] = d2;
        }
        __syncthreads();
        if (tid < 352) {  // horizontal: 22 halo rows x 16 out cols
            int r = tid >> 4, c = tid & 15;
            float s = 0.f;
#pragma unroll
            for (int d = 0; d < 7; d++) s += s_d2[r * 22 + c + d];
            s_hs[r * 16 + c] = s;
        }
        __syncthreads();
        if (tid < 256) {  // vertical: 16x16 outputs
            int i = tid >> 4, jj = tid & 15;
            float s = 0.f;
#pragma unroll
            for (int d = 0; d < 7; d++) s += s_hs[(i + d) * 16 + jj];
            int y = (h0 + i) * 128 + (w0 + jj);
            int o = di * 13 + dj;
            logits[o * HW + y] = -tinv[y] * s;
        }
        __syncthreads();
    }
}

// ---------------------------------------------------------------------------
// K2: K=7 rounds of exclusion softmax over O=169. grid 512 x 256.
// 32 pixels/block, 8 lanes per pixel (o strided by 8), logits AND the packed
// per-round weights held in registers; each (o,y) 16B cell written ONCE.
// (round 1 fix: was 7 strided 2B writes/cell -> 7x full-line writeback,
//  308MB HBM writes measured. Now: 44MB.)
// ---------------------------------------------------------------------------
__global__ __launch_bounds__(256) void k_softmax(
        const float* __restrict__ logits, u16* __restrict__ Wkt) {
    __shared__ float s_lg[169 * 34];
    int tid = threadIdx.x;
    int y0 = blockIdx.x * 32;
    for (int idx = tid; idx < 169 * 32; idx += 256) {
        int o = idx >> 5, p = idx & 31;
        s_lg[o * 34 + p] = logits[o * HW + y0 + p];
    }
    __syncthreads();
    int pix = tid >> 3, t = tid & 7;
    int y = y0 + pix;
    float l[22];
#pragma unroll
    for (int j = 0; j < 22; j++) {
        int o = t + 8 * j;
        l[j] = (o < 169) ? s_lg[o * 34 + pix] : -3e38f;
    }
    u32 wp0[22], wp1[22], wp2[22], wp3[22];
#pragma unroll
    for (int j = 0; j < 22; j++) { wp0[j] = 0u; wp1[j] = 0u; wp2[j] = 0u; wp3[j] = 0u; }

    float e[22];
#pragma unroll
    for (int k = 0; k < 7; k++) {
        float m = -3e38f;
#pragma unroll
        for (int j = 0; j < 22; j++) m = fmaxf(m, l[j]);
        m = fmaxf(m, __shfl_xor(m, 1));
        m = fmaxf(m, __shfl_xor(m, 2));
        m = fmaxf(m, __shfl_xor(m, 4));
        float s = 0.f;
#pragma unroll
        for (int j = 0; j < 22; j++) { e[j] = __expf(l[j] - m); s += e[j]; }
        s += __shfl_xor(s, 1);
        s += __shfl_xor(s, 2);
        s += __shfl_xor(s, 4);
        float rs = 1.0f / s;
#pragma unroll
        for (int j = 0; j < 22; j++) {
            float w = e[j] * rs;
            u32 h = (u32)f2bf(w);
            if (k == 0) wp0[j] |= h;
            else if (k == 1) wp0[j] |= h << 16;
            else if (k == 2) wp1[j] |= h;
            else if (k == 3) wp1[j] |= h << 16;
            else if (k == 4) wp2[j] |= h;
            else if (k == 5) wp2[j] |= h << 16;
            else wp3[j] |= h;
            if (k < 6) l[j] += __logf(fmaxf(1.0f - w, 1e-6f));
        }
    }
#pragma unroll
    for (int j = 0; j < 22; j++) {
        int o = t + 8 * j;
        if (o < 169)
            *reinterpret_cast<uint4*>(Wkt + (o * HW + y) * 8) =
                make_uint4(wp0[j], wp1[j], wp2[j], wp3[j]);
    }
}

// ---------------------------------------------------------------------------
// K2b: 7x7 boxsum of Wkt -> WsT[o][y][k8] bf16. grid (169, 16 tiles of 32x32).
// separable sliding-window, vectorized over packed k.
// ---------------------------------------------------------------------------
__global__ __launch_bounds__(256) void k_wsum(
        const u16* __restrict__ Wkt, u16* __restrict__ WsT) {
    __shared__ u16 s_w[38 * 38 * 8];
    __shared__ float s_v[32 * 38 * 8];
    int o = blockIdx.x;
    int tile = blockIdx.y;
    int h0 = (tile >> 2) * 32, w0 = (tile & 3) * 32;
    int tid = threadIdx.x;

    for (int idx = tid; idx < 38 * 38; idx += 256) {
        int r = idx / 38, c = idx - r * 38;
        int gy = h0 - 3 + r, gx = w0 - 3 + c;
        uint4 v = make_uint4(0u, 0u, 0u, 0u);
        if ((unsigned)gy < 128u && (unsigned)gx < 128u)
            v = *reinterpret_cast<const uint4*>(Wkt + (o * HW + gy * 128 + gx) * 8);
        *reinterpret_cast<uint4*>(s_w + idx * 8) = v;
    }
    __syncthreads();

    if (tid < 152) {  // vertical: 38 cols x 4 groups of 8 out-rows
        int c = tid >> 2, g = tid & 3;
        int r0 = g * 8;
        float acc[7];
#pragma unroll
        for (int k = 0; k < 7; k++) acc[k] = 0.f;
#pragma unroll
        for (int d = 0; d < 7; d++) {
            uint4 q = *reinterpret_cast<const uint4*>(s_w + ((r0 + d) * 38 + c) * 8);
            acc[0] += bf2f((u16)(q.x & 0xffffu)); acc[1] += bf2f((u16)(q.x >> 16));
            acc[2] += bf2f((u16)(q.y & 0xffffu)); acc[3] += bf2f((u16)(q.y >> 16));
            acc[4] += bf2f((u16)(q.z & 0xffffu)); acc[5] += bf2f((u16)(q.z >> 16));
            acc[6] += bf2f((u16)(q.w & 0xffffu));
        }
#pragma unroll
        for (int k = 0; k < 7; k++) s_v[(r0 * 38 + c) * 8 + k] = acc[k];
        for (int i = 1; i < 8; i++) {
            uint4 qn = *reinterpret_cast<const uint4*>(s_w + ((r0 + i + 6) * 38 + c) * 8);
            uint4 qo = *reinterpret_cast<const uint4*>(s_w + ((r0 + i - 1) * 38 + c) * 8);
            acc[0] += bf2f((u16)(qn.x & 0xffffu)) - bf2f((u16)(qo.x & 0xffffu));
            acc[1] += bf2f((u16)(qn.x >> 16)) - bf2f((u16)(qo.x >> 16));
            acc[2] += bf2f((u16)(qn.y & 0xffffu)) - bf2f((u16)(qo.y & 0xffffu));
            acc[3] += bf2f((u16)(qn.y >> 16)) - bf2f((u16)(qo.y >> 16));
            acc[4] += bf2f((u16)(qn.z & 0xffffu)) - bf2f((u16)(qo.z & 0xffffu));
            acc[5] += bf2f((u16)(qn.z >> 16)) - bf2f((u16)(qo.z >> 16));
            acc[6] += bf2f((u16)(qn.w & 0xffffu)) - bf2f((u16)(qo.w & 0xffffu));
#pragma unroll
            for (int k = 0; k < 7; k++) s_v[((r0 + i) * 38 + c) * 8 + k] = acc[k];
        }
    }
    __syncthreads();

    if (tid < 128) {  // horizontal: 32 rows x 4 groups of 8 out-cols
        int r = tid >> 2, g = tid & 3;
        int c0 = g * 8;
        float acc[7];
#pragma unroll
        for (int k = 0; k < 7; k++) acc[k] = 0.f;
        for (int d = 0; d < 7; d++) {
#pragma unroll
            for (int k = 0; k < 7; k++) acc[k] += s_v[(r * 38 + c0 + d) * 8 + k];
        }
        for (int i = 0; i < 8; i++) {
            if (i > 0) {
#pragma unroll
                for (int k = 0; k < 7; k++)
                    acc[k] += s_v[(r * 38 + c0 + i + 6) * 8 + k] - s_v[(r * 38 + c0 + i - 1) * 8 + k];
            }
            u32 p0 = (u32)f2bf(acc[0]) | ((u32)f2bf(acc[1]) << 16);
            u32 p1 = (u32)f2bf(acc[2]) | ((u32)f2bf(acc[3]) << 16);
            u32 p2 = (u32)f2bf(acc[4]) | ((u32)f2bf(acc[5]) << 16);
            u32 p3 = (u32)f2bf(acc[6]);
            int y = (h0 + r) * 128 + (w0 + c0 + i);
            *reinterpret_cast<uint4*>(WsT + (o * HW + y) * 8) = make_uint4(p0, p1, p2, p3);
        }
    }
}

// ---------------------------------------------------------------------------
// K3: aggregation. out[k,c,y] = sum_o WsT[o,y,k] * x[c, y+off(o)].
// grid 256 tiles of 4x16 pixels, 512 threads = 64 pixels x 8 c-chunks.
// acc[7][8] in registers: x value reused across all 7 k.
// ---------------------------------------------------------------------------
__global__ __launch_bounds__(512) void k_agg(
        const u16* __restrict__ xT, const u16* __restrict__ WsT,
        float* __restrict__ out) {
    __shared__ u16 s_x[448 * 68];     // [16r x 28c][64ch pad 68]
    __shared__ u16 s_ws[7 * 64 * 12]; // [j][pix][8k pad 12]
    int tb = blockIdx.x;
    int h0 = (tb >> 3) * 4, w0 = (tb & 7) * 16;
    int tid = threadIdx.x;

    for (int idx = tid; idx < 448 * 16; idx += 512) {
        int cell = idx >> 4, ch = idx & 15;
        int r = cell / 28, c = cell - r * 28;
        int gy = h0 - 6 + r, gx = w0 - 6 + c;
        uint2 v = make_uint2(0u, 0u);
        if ((unsigned)gy < 128u && (unsigned)gx < 128u)
            v = *reinterpret_cast<const uint2*>(xT + (gy * 128 + gx) * 64 + ch * 4);
        *reinterpret_cast<uint2*>(s_x + cell * 68 + ch * 4) = v;
    }

    int cc = tid >> 6, pix = tid & 63;
    int pr = pix >> 4, pc = pix & 15;
    int y = (h0 + pr) * 128 + (w0 + pc);
    float acc[7][8];
#pragma unroll
    for (int k = 0; k < 7; k++)
#pragma unroll
        for (int q = 0; q < 8; q++) acc[k][q] = 0.f;

    for (int oc = 0; oc < 25; oc++) {
        int o0 = oc * 7;
        int nj = (169 - o0 < 7) ? (169 - o0) : 7;
        __syncthreads();
        if (tid < nj * 64) {
            int j = tid >> 6, p = tid & 63;
            int yy = (h0 + (p >> 4)) * 128 + (w0 + (p & 15));
            uint4 q = *reinterpret_cast<const uint4*>(WsT + ((o0 + j) * HW + yy) * 8);
            *reinterpret_cast<uint2*>(s_ws + (j * 64 + p) * 12) = make_uint2(q.x, q.y);
            *reinterpret_cast<uint2*>(s_ws + (j * 64 + p) * 12 + 4) = make_uint2(q.z, q.w);
        }
        __syncthreads();
#pragma unroll 1
        for (int j = 0; j < nj; j++) {
            int o = o0 + j;
            int di = o / 13, dj = o - di * 13;
            uint2 wa = *reinterpret_cast<const uint2*>(s_ws + (j * 64 + pix) * 12);
            uint2 wb = *reinterpret_cast<const uint2*>(s_ws + (j * 64 + pix) * 12 + 4);
            float wv[7];
            wv[0] = bf2f((u16)(wa.x & 0xffffu)); wv[1] = bf2f((u16)(wa.x >> 16));
            wv[2] = bf2f((u16)(wa.y & 0xffffu)); wv[3] = bf2f((u16)(wa.y >> 16));
            wv[4] = bf2f((u16)(wb.x & 0xffffu)); wv[5] = bf2f((u16)(wb.x >> 16));
            wv[6] = bf2f((u16)(wb.y & 0xffffu));
            int cell = (pr + di) * 28 + (pc + dj);
            const u16* xp = s_x + cell * 68 + cc * 8;
            uint2 xa = *reinterpret_cast<const uint2*>(xp);
            uint2 xb = *reinterpret_cast<const uint2*>(xp + 4);
            float xv[8];
            xv[0] = bf2f((u16)(xa.x & 0xffffu)); xv[1] = bf2f((u16)(xa.x >> 16));
            xv[2] = bf2f((u16)(xa.y & 0xffffu)); xv[3] = bf2f((u16)(xa.y >> 16));
            xv[4] = bf2f((u16)(xb.x & 0xffffu)); xv[5] = bf2f((u16)(xb.x >> 16));
            xv[6] = bf2f((u16)(xb.y & 0xffffu)); xv[7] = bf2f((u16)(xb.y >> 16));
#pragma unroll
            for (int k = 0; k < 7; k++)
#pragma unroll
                for (int q = 0; q < 8; q++)
                    acc[k][q] = fmaf(wv[k], xv[q], acc[k][q]);
        }
    }
#pragma unroll
    for (int k = 0; k < 7; k++)
#pragma unroll
        for (int q = 0; q < 8; q++)
            out[(k * 64 + cc * 8 + q) * HW + y] = acc[k][q];
}

// ---------------------------------------------------------------------------
extern "C" void kernel_launch(void* const* d_in, const int* in_sizes, int n_in,
                              void* d_out, int out_size, void* d_ws, size_t ws_size,
                              hipStream_t stream) {
    (void)in_sizes; (void)n_in; (void)out_size; (void)ws_size;
    const float* x  = (const float*)d_in[0];
    const float* xe = (const float*)d_in[1];
    const float* ye = (const float*)d_in[2];
    const float* lt = (const float*)d_in[3];
    float* out = (float*)d_out;
    char* ws = (char*)d_ws;

    u16*   xT     = (u16*)(ws + 0);            //  2,097,152 B
    float* xeT    = (float*)(ws + 2097152u);   //  2,097,152
    float* yeT    = (float*)(ws + 4194304u);   //  2,097,152
    float* tinv   = (float*)(ws + 6291456u);   //     65,536
    float* logits = (float*)(ws + 6356992u);   // 11,075,584
    u16*   Wkt    = (u16*)(ws + 17432576u);    // 44,302,336
    u16*   WsT    = (u16*)(ws + 61734912u);    // 44,302,336 -> ends 106,037,248

    k_prep<<<64, 256, 0, stream>>>(x, xe, ye, lt, xT, xeT, yeT, tinv);
    k_logits<<<dim3(13, 64), 512, 0, stream>>>(xeT, yeT, tinv, logits);
    k_softmax<<<512, 256, 0, stream>>>(logits, Wkt);
    k_wsum<<<dim3(169, 16), 256, 0, stream>>>(Wkt, WsT);
    k_agg<<<256, 512, 0, stream>>>(xT, WsT, out);
}